// Round 8
// baseline (270.823 us; speedup 1.0000x reference)
//
#include <hip/hip_runtime.h>

// (B,C,T)=(8,512,1024), H=8, D=64, K=64, REL=129. I/O fp32; internal bf16.
#define B_   8
#define C_   512
#define T_   1024
#define H_   8
#define D_   64
#define K_   64
#define REL_ 129

typedef unsigned short u16;
typedef __attribute__((ext_vector_type(8))) short short8;   // 8 bf16 (4 VGPRs)
typedef __attribute__((ext_vector_type(4))) float f32x4;

__device__ __forceinline__ float b2f(u16 u) {
    return __uint_as_float(((unsigned)u) << 16);
}
__device__ __forceinline__ u16 f2b(float f) {
    unsigned x = __float_as_uint(f);
    x += 0x7fffu + ((x >> 16) & 1u);   // RNE
    return (u16)(x >> 16);
}

// ---------------------------------------------------------------------------
// Kernel 0: all input casts in one launch.
//   blk [0,1024)    : x -> xt[b][t][c] bf16 (transpose)
//   blk [1024,2048) : Wq/Wk/Wv/Wo -> Wh[4][512][512] bf16
//   blk [2048,2121) : ervt[d][rel] [64][160] pad0 ; erkb[rel][d] [129][64]
// ---------------------------------------------------------------------------
__global__ __launch_bounds__(256) void cast_all_kernel(
    const float* __restrict__ x,
    const float* __restrict__ Wq, const float* __restrict__ Wk,
    const float* __restrict__ Wv, const float* __restrict__ Wo,
    const float* __restrict__ erk, const float* __restrict__ erv,
    u16* __restrict__ xt, u16* __restrict__ Wh,
    u16* __restrict__ ervt, u16* __restrict__ erkb)
{
    __shared__ u16 tile[64][72];
    const int blk = blockIdx.x;
    const int tid = threadIdx.x;
    if (blk < 1024) {
        const int t0 = (blk & 15) * 64, c0 = ((blk >> 4) & 7) * 64, b = blk >> 7;
        const int f = tid & 15, r0 = tid >> 4;
#pragma unroll
        for (int p = 0; p < 4; ++p) {
            const int c = r0 + p * 16;
            const float4 v = *(const float4*)(x + ((size_t)b * C_ + c0 + c) * T_ + t0 + f * 4);
            tile[c][f * 4 + 0] = f2b(v.x);
            tile[c][f * 4 + 1] = f2b(v.y);
            tile[c][f * 4 + 2] = f2b(v.z);
            tile[c][f * 4 + 3] = f2b(v.w);
        }
        __syncthreads();
#pragma unroll
        for (int p = 0; p < 4; ++p) {
            const int t = r0 + p * 16;
            ushort4 u;
            u.x = tile[f * 4 + 0][t];
            u.y = tile[f * 4 + 1][t];
            u.z = tile[f * 4 + 2][t];
            u.w = tile[f * 4 + 3][t];
            *(ushort4*)(xt + ((size_t)b * T_ + t0 + t) * C_ + c0 + f * 4) = u;
        }
    } else if (blk < 2048) {
        const int gid = (blk - 1024) * 256 + tid;
        const int s = gid >> 16;
        const int off = (gid & 65535) * 4;
        const float* W = (s == 0) ? Wq : (s == 1) ? Wk : (s == 2) ? Wv : Wo;
        const float4 v = *(const float4*)(W + off);
        ushort4 u;
        u.x = f2b(v.x); u.y = f2b(v.y); u.z = f2b(v.z); u.w = f2b(v.w);
        *(ushort4*)(Wh + ((size_t)s << 18) + off) = u;
    } else {
        const int idx = (blk - 2048) * 256 + tid;
        if (idx < 64 * 160) {
            const int d = idx / 160, rel = idx % 160;
            ervt[idx] = (rel < REL_) ? f2b(erv[rel * D_ + d]) : (u16)0;
        } else {
            const int j = idx - 64 * 160;
            if (j < REL_ * D_) erkb[j] = f2b(erk[j]);
        }
    }
}

// ---------------------------------------------------------------------------
// Kernel 1 v4: QKV projection, split q/k/v, t-tile 128 (v3 structure), plus
// V epilogue transposed through LDS (aliased over dead Wt, two passes) ->
// coalesced 128B-contiguous vt stores. v3's direct vt store was a 2B-at-2KB
// -stride scatter: 16 granules/instr at 6% efficiency, ~128 MB physical
// writes for 8 MB logical. grid = (T/128, H, 3*B), block 256, LDS 9.2 KB.
// ---------------------------------------------------------------------------
__global__ __launch_bounds__(256) void proj_mfma(
    const u16* __restrict__ xt, const u16* __restrict__ Wh,
    const float* __restrict__ bq, const float* __restrict__ bk, const float* __restrict__ bv,
    u16* __restrict__ qh, u16* __restrict__ kh, u16* __restrict__ vt)
{
    __shared__ u16 Wt[64][72];

    const int t0 = blockIdx.x * 128;
    const int h  = blockIdx.y;
    const int sel = blockIdx.z >> 3;
    const int b   = blockIdx.z & 7;
    const int tid = threadIdx.x, wave = tid >> 6, lane = tid & 63;
    const int quad = lane >> 4, l16 = lane & 15;

    const u16* Wbase = Wh + ((size_t)sel << 18) + ((size_t)(h * 64) << 9);
    const u16* A0 = xt + (((size_t)b * T_ + t0 + wave * 16 + l16) << 9);
    const u16* A1 = A0 + ((size_t)64 << 9);

    const int so = tid >> 2;
    const int sc = (tid & 3) * 16;
    const u16* wsrc = Wbase + ((size_t)so << 9) + sc;

    f32x4 acc[2][4];
#pragma unroll
    for (int gg = 0; gg < 2; ++gg)
#pragma unroll
        for (int nt = 0; nt < 4; ++nt) acc[gg][nt] = (f32x4){0.f, 0.f, 0.f, 0.f};

    uint4 wv0 = *(const uint4*)(wsrc);
    uint4 wv1 = *(const uint4*)(wsrc + 8);
#pragma unroll 1
    for (int i = 0; i < 8; ++i) {
        const int c0 = i * 64;
        __syncthreads();
        *(uint4*)&Wt[so][sc] = wv0;
        *(uint4*)&Wt[so][sc + 8] = wv1;
        __syncthreads();
        if (i < 7) {
            wv0 = *(const uint4*)(wsrc + c0 + 64);
            wv1 = *(const uint4*)(wsrc + c0 + 72);
        }
#pragma unroll
        for (int kk = 0; kk < 64; kk += 32) {
            const short8 af0 = *(const short8*)(A0 + c0 + kk + quad * 8);
            const short8 af1 = *(const short8*)(A1 + c0 + kk + quad * 8);
#pragma unroll
            for (int nt = 0; nt < 4; ++nt) {
                const short8 bf = *(const short8*)(&Wt[nt * 16 + l16][kk + quad * 8]);
                acc[0][nt] = __builtin_amdgcn_mfma_f32_16x16x32_bf16(af0, bf, acc[0][nt], 0, 0, 0);
                acc[1][nt] = __builtin_amdgcn_mfma_f32_16x16x32_bf16(af1, bf, acc[1][nt], 0, 0, 0);
            }
        }
    }

    const int bh = b * 8 + h;
    if (sel == 2) {
        // V: transpose through LDS (reuse Wt, two t-64 passes), coalesced out
#pragma unroll 1
        for (int gg = 0; gg < 2; ++gg) {
            __syncthreads();
#pragma unroll
            for (int nt = 0; nt < 4; ++nt) {
                const int d = nt * 16 + l16;
                const float bo = bv[h * 64 + d];
#pragma unroll
                for (int rix = 0; rix < 4; ++rix) {
                    const int tl = wave * 16 + quad * 4 + rix;
                    Wt[d][tl] = f2b(acc[gg][nt][rix] + bo);
                }
            }
            __syncthreads();
            const int row = tid >> 2;         // 0..63 (d)
            const int seg = (tid & 3) * 16;   // 0,16,32,48 (t within 64)
            const uint4 v0 = *(const uint4*)&Wt[row][seg];
            const uint4 v1 = *(const uint4*)&Wt[row][seg + 8];
            u16* vdst = vt + (((size_t)bh * 64 + row) << 10) + t0 + gg * 64 + seg;
            *(uint4*)(vdst) = v0;
            *(uint4*)(vdst + 8) = v1;
        }
    } else {
        const float* bias = sel ? bk : bq;
        u16* dst = sel ? kh : qh;
#pragma unroll
        for (int nt = 0; nt < 4; ++nt) {
            const int d = nt * 16 + l16;
            const float bo = bias[h * 64 + d];
#pragma unroll
            for (int gg = 0; gg < 2; ++gg)
#pragma unroll
                for (int rix = 0; rix < 4; ++rix) {
                    const int t = t0 + gg * 64 + wave * 16 + quad * 4 + rix;
                    dst[(((size_t)bh * T_ + t) << 6) + d] = f2b(acc[gg][nt][rix] + bo);
                }
        }
    }
}

// ---------------------------------------------------------------------------
// Kernel 2: MFMA attention. v6 (kept): 32 q-rows, 256 thr / 4 waves,
// j-quarter per wave, exp2-domain math, cvt_pk packing, cross-iteration
// register prefetch of K/xmask/V. grid = 2048 (XCD-swizzled), block 256.
// LDS ~78 KB -> 2 blocks/CU.
// ---------------------------------------------------------------------------
__global__ __launch_bounds__(256, 2) void attn_kernel(
    const u16* __restrict__ qh, const u16* __restrict__ kh, const u16* __restrict__ vt,
    const u16* __restrict__ erkb, const u16* __restrict__ ervt,
    const float* __restrict__ xmask, u16* __restrict__ yf)
{
    __shared__ u16   Sb[32][1032];     // raw exp(score) bf16; later og staging
    __shared__ u16   sw[32][168];      // phase A: srel*log2e; phase B: wrel (raw)
    __shared__ float red[4][32][2];    // per-wave {sum, phi}
    __shared__ float invrow[32];

    const int gid = blockIdx.x;
    const int x8 = gid & 7, r5 = gid >> 3;
    const int bh = x8 + 8 * (r5 >> 5);
    const int i0 = (r5 & 31) * 32;
    const int b = bh >> 3, h = bh & 7;
    const int tid = threadIdx.x, wave = tid >> 6, lane = tid & 63;
    const int quad = lane >> 4, l16 = lane & 15;

    const float LOG2E = 1.4426950408889634f;
    const float SC    = 0.125f * 1.4426950408889634f;   // qk scale in exp2 domain

    // Q A-frags for both 16-row groups
    short8 qa[2][2];
#pragma unroll
    for (int g = 0; g < 2; ++g) {
        const u16* qrow = qh + (((size_t)bh * T_ + i0 + g * 16 + l16) << 6);
        qa[g][0] = *(const short8*)(qrow + quad * 8);
        qa[g][1] = *(const short8*)(qrow + 32 + quad * 8);
    }

    // ---- phase 1: srel via MFMA (stored pre-scaled by log2e) ----
    for (int tile = wave; tile < 9; tile += 4) {
        const int rel = tile * 16 + l16;
        const int rl = rel > 128 ? 128 : rel;
        const u16* ep = erkb + rl * 64 + quad * 8;
        const short8 b0 = *(const short8*)(ep);
        const short8 b1 = *(const short8*)(ep + 32);
#pragma unroll
        for (int g = 0; g < 2; ++g) {
            f32x4 m = {0.f, 0.f, 0.f, 0.f};
            m = __builtin_amdgcn_mfma_f32_16x16x32_bf16(qa[g][0], b0, m, 0, 0, 0);
            m = __builtin_amdgcn_mfma_f32_16x16x32_bf16(qa[g][1], b1, m, 0, 0, 0);
            if (rel < 129) {
#pragma unroll
                for (int rix = 0; rix < 4; ++rix)
                    sw[g * 16 + quad * 4 + rix][rel] = f2b(m[rix] * LOG2E);
            }
        }
    }
    __syncthreads();                                    // barrier 1

    // srel constants for fully-clamped tiles (exp2 domain)
    float slo_c[2][4], shi_c[2][4];
#pragma unroll
    for (int g = 0; g < 2; ++g)
#pragma unroll
        for (int rix = 0; rix < 4; ++rix) {
            const int row = g * 16 + quad * 4 + rix;
            slo_c[g][rix] = b2f(sw[row][0]);
            shi_c[g][rix] = b2f(sw[row][2 * K_]);
        }

    // ---- merged QK + exp + partial-PV over this wave's j-quarter ----
    float psum[2][4] = {{0.f,0.f,0.f,0.f},{0.f,0.f,0.f,0.f}};
    float phi [2][4] = {{0.f,0.f,0.f,0.f},{0.f,0.f,0.f,0.f}};
    f32x4 og[4][2];
#pragma unroll
    for (int s = 0; s < 4; ++s)
#pragma unroll
        for (int g = 0; g < 2; ++g) og[s][g] = (f32x4){0.f, 0.f, 0.f, 0.f};

    {
        const u16* kb = kh + ((size_t)bh << 16);
        const u16* vbase = vt + ((size_t)bh << 16);

        // ---- prefetch registers: K/mask one j-tile ahead, V one chunk ahead
        short8 kc0, kc1;
        float  xmc;
        {
            const u16* krow0 = kb + ((size_t)(wave * 256 + l16) << 6);
            kc0 = *(const short8*)(krow0 + quad * 8);
            kc1 = *(const short8*)(krow0 + 32 + quad * 8);
            xmc = xmask[b * T_ + wave * 256 + l16];
        }
        short8 vaf[4];
#pragma unroll
        for (int s = 0; s < 4; ++s)
            vaf[s] = *(const short8*)(vbase + ((size_t)(s * 16 + l16) << 10) + wave * 256 + quad * 8);

#pragma unroll 1
        for (int c = 0; c < 8; ++c) {
#pragma unroll
            for (int half = 0; half < 2; ++half) {
                const int ct = c * 2 + half;
                const int j0 = wave * 256 + ct * 16;
                const int j = j0 + l16;
                // rotate current, issue next-tile loads (clamped on last)
                const short8 kb0 = kc0, kb1 = kc1;
                const float xmv = xmc;
                {
                    const int jn = wave * 256 + ((ct < 15) ? ct + 1 : ct) * 16 + l16;
                    const u16* krown = kb + ((size_t)jn << 6);
                    kc0 = *(const short8*)(krown + quad * 8);
                    kc1 = *(const short8*)(krown + 32 + quad * 8);
                    xmc = xmask[b * T_ + jn];
                }
                // masked lanes clamp to -2e9 -> exp2 -> 0
                const float clampv = (xmv > 0.f) ? 43.280850f : -2.0e9f;
#pragma unroll
                for (int g = 0; g < 2; ++g) {
                    f32x4 acc = {0.f, 0.f, 0.f, 0.f};
                    acc = __builtin_amdgcn_mfma_f32_16x16x32_bf16(qa[g][0], kb0, acc, 0, 0, 0);
                    acc = __builtin_amdgcn_mfma_f32_16x16x32_bf16(qa[g][1], kb1, acc, 0, 0, 0);
                    const int dd = j0 - (i0 + g * 16);
                    const int ibase = i0 + g * 16 + quad * 4;
                    float ee[4];
                    if (dd <= -79) {
#pragma unroll
                        for (int rix = 0; rix < 4; ++rix)
                            ee[rix] = __builtin_amdgcn_exp2f(
                                fminf(fmaf(acc[rix], SC, slo_c[g][rix]), clampv));
                    } else if (dd >= 79) {
#pragma unroll
                        for (int rix = 0; rix < 4; ++rix)
                            ee[rix] = __builtin_amdgcn_exp2f(
                                fminf(fmaf(acc[rix], SC, shi_c[g][rix]), clampv));
                    } else {
                        const int relb = j - ibase + K_;
#pragma unroll
                        for (int rix = 0; rix < 4; ++rix) {
                            int idx = relb - rix;
                            idx = idx < 0 ? 0 : (idx > 2 * K_ ? 2 * K_ : idx);
                            const int row = g * 16 + quad * 4 + rix;
                            const float sr = b2f(sw[row][idx]);
                            ee[rix] = __builtin_amdgcn_exp2f(
                                fminf(fmaf(acc[rix], SC, sr), clampv));
                        }
                    }
                    // pack to bf16 pairs (RNE), store, accumulate rounded values
                    unsigned p01, p23;
                    asm("v_cvt_pk_bf16_f32 %0, %1, %2" : "=v"(p01) : "v"(ee[0]), "v"(ee[1]));
                    asm("v_cvt_pk_bf16_f32 %0, %1, %2" : "=v"(p23) : "v"(ee[2]), "v"(ee[3]));
                    const int r0 = g * 16 + quad * 4;
                    Sb[r0 + 0][j] = (u16)(p01 & 0xffffu);
                    Sb[r0 + 1][j] = (u16)(p01 >> 16);
                    Sb[r0 + 2][j] = (u16)(p23 & 0xffffu);
                    Sb[r0 + 3][j] = (u16)(p23 >> 16);
                    const float er0 = __uint_as_float(p01 << 16);
                    const float er1 = __uint_as_float(p01 & 0xffff0000u);
                    const float er2 = __uint_as_float(p23 << 16);
                    const float er3 = __uint_as_float(p23 & 0xffff0000u);
                    psum[g][0] += er0; psum[g][1] += er1;
                    psum[g][2] += er2; psum[g][3] += er3;
                    if (dd >= 79) {
                        phi[g][0] += er0; phi[g][1] += er1;
                        phi[g][2] += er2; phi[g][3] += er3;
                    } else if (dd > -79) {
                        phi[g][0] += (j - ibase >= 64) ? er0 : 0.f;
                        phi[g][1] += (j - ibase >= 65) ? er1 : 0.f;
                        phi[g][2] += (j - ibase >= 66) ? er2 : 0.f;
                        phi[g][3] += (j - ibase >= 67) ? er3 : 0.f;
                    }
                }
            }
            // partial PV for this 32-column chunk (same-wave data, no barrier)
            const int kc = wave * 256 + c * 32;
            const short8 pb0 = *(const short8*)(&Sb[l16][kc + quad * 8]);
            const short8 pb1 = *(const short8*)(&Sb[16 + l16][kc + quad * 8]);
            // prefetch V for next chunk (clamped on last)
            short8 vn[4];
            {
                const int kcn = wave * 256 + ((c < 7) ? c + 1 : c) * 32;
#pragma unroll
                for (int s = 0; s < 4; ++s)
                    vn[s] = *(const short8*)(vbase + ((size_t)(s * 16 + l16) << 10) + kcn + quad * 8);
            }
#pragma unroll
            for (int s = 0; s < 4; ++s) {
                og[s][0] = __builtin_amdgcn_mfma_f32_16x16x32_bf16(vaf[s], pb0, og[s][0], 0, 0, 0);
                og[s][1] = __builtin_amdgcn_mfma_f32_16x16x32_bf16(vaf[s], pb1, og[s][1], 0, 0, 0);
            }
#pragma unroll
            for (int s = 0; s < 4; ++s) vaf[s] = vn[s];
        }
#pragma unroll
        for (int m = 1; m < 16; m <<= 1)
#pragma unroll
            for (int g = 0; g < 2; ++g)
#pragma unroll
                for (int rix = 0; rix < 4; ++rix) {
                    psum[g][rix] += __shfl_xor(psum[g][rix], m);
                    phi[g][rix]  += __shfl_xor(phi[g][rix], m);
                }
        if (l16 == 0)
#pragma unroll
            for (int g = 0; g < 2; ++g)
#pragma unroll
                for (int rix = 0; rix < 4; ++rix) {
                    const int row = g * 16 + quad * 4 + rix;
                    red[wave][row][0] = psum[g][rix];
                    red[wave][row][1] = phi[g][rix];
                }
    }
    __syncthreads();                                    // barrier 2

    // ---- wrel (raw) from Sb; slo by complement; invrow ----
    {
        const int rr = tid >> 3;        // 0..31
        const int c0 = tid & 7;
        const float sumrow = red[0][rr][0] + red[1][rr][0] + red[2][rr][0] + red[3][rr][0];
        const float phirow = red[0][rr][1] + red[1][rr][1] + red[2][rr][1] + red[3][rr][1];
        float intsum = 0.f;
        for (int rel = c0; rel < 168; rel += 8) {
            if (rel == 0 || rel == 2 * K_) continue;
            u16 v = 0;
            if (rel < 2 * K_) {
                const int j = i0 + rr + rel - K_;
                if (j >= 0 && j < T_) v = Sb[rr][j];
                intsum += b2f(v);
            }
            sw[rr][rel] = v;
        }
        intsum += __shfl_xor(intsum, 1);
        intsum += __shfl_xor(intsum, 2);
        intsum += __shfl_xor(intsum, 4);
        if (c0 == 0) {
            sw[rr][2 * K_] = f2b(phirow);
            sw[rr][0]      = f2b(sumrow - intsum - phirow);
            invrow[rr]     = 1.0f / sumrow;
        }
    }
    __syncthreads();                                    // barrier 3

    // ---- stage og partials into LDS (aliased over dead Sb rows) ----
    float* fog = (float*)&Sb[0][0];                     // 4 waves x 2048 floats = 32 KB
#pragma unroll
    for (int s = 0; s < 4; ++s)
#pragma unroll
        for (int g = 0; g < 2; ++g)
            *(f32x4*)&fog[wave * 2048 + ((s * 2 + g) * 64 + lane) * 4] = og[s][g];
    __syncthreads();                                    // barrier 4

    // ---- owner wave (strip = wave): reduce 4 partials + rel-v MFMA; store ----
    {
        const int dh = wave * 16 + l16;
        const u16* ep = ervt + dh * 160;
        f32x4 accg[2];
#pragma unroll
        for (int g = 0; g < 2; ++g) {
            const int base = ((wave * 2 + g) * 64 + lane) * 4;
            f32x4 a0 = *(const f32x4*)&fog[base];
            f32x4 a1 = *(const f32x4*)&fog[2048 + base];
            f32x4 a2 = *(const f32x4*)&fog[4096 + base];
            f32x4 a3 = *(const f32x4*)&fog[6144 + base];
#pragma unroll
            for (int rix = 0; rix < 4; ++rix)
                accg[g][rix] = (a0[rix] + a1[rix]) + (a2[rix] + a3[rix]);
        }
#pragma unroll
        for (int kt = 0; kt < 5; ++kt) {
            const short8 af = *(const short8*)(ep + kt * 32 + quad * 8);
            const short8 p0 = *(const short8*)(&sw[l16][kt * 32 + quad * 8]);
            const short8 p1 = *(const short8*)(&sw[16 + l16][kt * 32 + quad * 8]);
            accg[0] = __builtin_amdgcn_mfma_f32_16x16x32_bf16(af, p0, accg[0], 0, 0, 0);
            accg[1] = __builtin_amdgcn_mfma_f32_16x16x32_bf16(af, p1, accg[1], 0, 0, 0);
        }
        const int dbase = (h << 6) + wave * 16 + quad * 4;
#pragma unroll
        for (int g = 0; g < 2; ++g) {
            const float iv = invrow[g * 16 + l16];
            ushort4 u;
            u.x = f2b(accg[g][0] * iv); u.y = f2b(accg[g][1] * iv);
            u.z = f2b(accg[g][2] * iv); u.w = f2b(accg[g][3] * iv);
            *(ushort4*)(yf + (((size_t)b * T_ + i0 + g * 16 + l16) << 9) + dbase) = u;
        }
    }
}

// ---------------------------------------------------------------------------
// Kernel 3: output projection via MFMA (R8 64-tile). yf tile staged in LDS.
// grid = (C/64, B*T/64), block 256.
// ---------------------------------------------------------------------------
__global__ __launch_bounds__(256) void outproj_mfma(
    const u16* __restrict__ yf, const u16* __restrict__ Woh, const float* __restrict__ bo,
    const float* __restrict__ xmask, float* __restrict__ out)
{
    __shared__ u16 Yt[64][72];

    const int o0 = blockIdx.x * 64;
    const int b  = blockIdx.y >> 4;
    const int t0 = (blockIdx.y & 15) * 64;
    const int tid = threadIdx.x, wave = tid >> 6, lane = tid & 63;
    const int quad = lane >> 4, l16 = lane & 15;

    const u16* A = Woh + ((size_t)(o0 + wave * 16 + l16) << 9);

    const int so = tid >> 2;
    const int sc = (tid & 3) * 16;
    const u16* ysrc = yf + (((size_t)b * T_ + t0 + so) << 9) + sc;

    f32x4 acc[4] = {{0.f,0.f,0.f,0.f},{0.f,0.f,0.f,0.f},{0.f,0.f,0.f,0.f},{0.f,0.f,0.f,0.f}};

    uint4 wv0 = *(const uint4*)(ysrc);
    uint4 wv1 = *(const uint4*)(ysrc + 8);
#pragma unroll 1
    for (int i = 0; i < 8; ++i) {
        const int c0 = i * 64;
        __syncthreads();
        *(uint4*)&Yt[so][sc] = wv0;
        *(uint4*)&Yt[so][sc + 8] = wv1;
        __syncthreads();
        if (i < 7) {
            wv0 = *(const uint4*)(ysrc + c0 + 64);
            wv1 = *(const uint4*)(ysrc + c0 + 72);
        }
#pragma unroll
        for (int kk = 0; kk < 64; kk += 32) {
            const short8 af = *(const short8*)(A + c0 + kk + quad * 8);
#pragma unroll
            for (int nt = 0; nt < 4; ++nt) {
                const short8 bf = *(const short8*)(&Yt[nt * 16 + l16][kk + quad * 8]);
                acc[nt] = __builtin_amdgcn_mfma_f32_16x16x32_bf16(af, bf, acc[nt], 0, 0, 0);
            }
        }
    }

#pragma unroll
    for (int nt = 0; nt < 4; ++nt) {
        const int t = t0 + nt * 16 + l16;
        const float xmv = xmask[b * T_ + t];
#pragma unroll
        for (int rix = 0; rix < 4; ++rix) {
            const int o = o0 + wave * 16 + quad * 4 + rix;
            out[((size_t)b * C_ + o) * T_ + t] = (acc[nt][rix] + bo[o]) * xmv;
        }
    }
}

// ---------------------------------------------------------------------------
extern "C" void kernel_launch(void* const* d_in, const int* in_sizes, int n_in,
                              void* d_out, int out_size, void* d_ws, size_t ws_size,
                              hipStream_t stream) {
    const float* x     = (const float*)d_in[0];
    const float* xmask = (const float*)d_in[1];
    const float* Wq    = (const float*)d_in[2];
    const float* bq    = (const float*)d_in[3];
    const float* Wk    = (const float*)d_in[4];
    const float* bk    = (const float*)d_in[5];
    const float* Wv    = (const float*)d_in[6];
    const float* bv    = (const float*)d_in[7];
    const float* Wo    = (const float*)d_in[8];
    const float* bo    = (const float*)d_in[9];
    const float* erk   = (const float*)d_in[10];
    const float* erv   = (const float*)d_in[11];

    // workspace (bf16):
    //   xt [B,T,C]    @ 0         (8 MB)
    //   Wh [4,C,C]    @ 8 MB      (2 MB)
    //   qh [B,H,T,D]  @ 10 MB     (8 MB)
    //   kh            @ 18 MB     (8 MB)
    //   vt [B,H,D,T]  @ 26 MB     (8 MB)
    //   yf [B,T,C]    @ 34 MB     (8 MB)
    //   ervt [64,160] @ 44040192  (20480 B)
    //   erkb [129,64] @ 44060672  (16512 B)
    const size_t need = 44077184;
    if (ws_size < need) return;
    u16* xt   = (u16*)d_ws;
    u16* Wh   = (u16*)((char*)d_ws + 8388608);
    u16* qh   = (u16*)((char*)d_ws + 10485760);
    u16* kh   = (u16*)((char*)d_ws + 18874368);
    u16* vt   = (u16*)((char*)d_ws + 27262976);
    u16* yf   = (u16*)((char*)d_ws + 35651584);
    u16* ervt = (u16*)((char*)d_ws + 44040192);
    u16* erkb = (u16*)((char*)d_ws + 44060672);
    float* out = (float*)d_out;

    cast_all_kernel<<<dim3(2121), 256, 0, stream>>>(
        x, Wq, Wk, Wv, Wo, erk, erv, xt, Wh, ervt, erkb);
    proj_mfma<<<dim3(T_ / 128, H_, 3 * B_), 256, 0, stream>>>(
        xt, Wh, bq, bk, bv, qh, kh, vt);
    attn_kernel<<<dim3(2048), 256, 0, stream>>>(
        qh, kh, vt, erkb, ervt, xmask, yf);
    outproj_mfma<<<dim3(C_ / 64, B_ * (T_ / 64)), 256, 0, stream>>>(
        yf, Wh + ((size_t)3 << 18), bo, xmask, out);
}

// Round 9
// 225.404 us; speedup vs baseline: 1.2015x; 1.2015x over previous
//
#include <hip/hip_runtime.h>

// (B,C,T)=(8,512,1024), H=8, D=64, K=64, REL=129. I/O fp32; internal bf16.
#define B_   8
#define C_   512
#define T_   1024
#define H_   8
#define D_   64
#define K_   64
#define REL_ 129

typedef unsigned short u16;
typedef __attribute__((ext_vector_type(8))) short short8;   // 8 bf16 (4 VGPRs)
typedef __attribute__((ext_vector_type(4))) float f32x4;

__device__ __forceinline__ float b2f(u16 u) {
    return __uint_as_float(((unsigned)u) << 16);
}
__device__ __forceinline__ u16 f2b(float f) {
    unsigned x = __float_as_uint(f);
    x += 0x7fffu + ((x >> 16) & 1u);   // RNE
    return (u16)(x >> 16);
}

// ---------------------------------------------------------------------------
// Kernel 0: all input casts in one launch.
//   blk [0,1024)    : x -> xt[b][t][c] bf16 (transpose)
//   blk [1024,2048) : Wq/Wk/Wv/Wo -> Wh[4][512][512] bf16
//   blk [2048,2121) : ervt[d][rel] [64][160] pad0 ; erkb[rel][d] [129][64]
// ---------------------------------------------------------------------------
__global__ __launch_bounds__(256) void cast_all_kernel(
    const float* __restrict__ x,
    const float* __restrict__ Wq, const float* __restrict__ Wk,
    const float* __restrict__ Wv, const float* __restrict__ Wo,
    const float* __restrict__ erk, const float* __restrict__ erv,
    u16* __restrict__ xt, u16* __restrict__ Wh,
    u16* __restrict__ ervt, u16* __restrict__ erkb)
{
    __shared__ u16 tile[64][72];
    const int blk = blockIdx.x;
    const int tid = threadIdx.x;
    if (blk < 1024) {
        const int t0 = (blk & 15) * 64, c0 = ((blk >> 4) & 7) * 64, b = blk >> 7;
        const int f = tid & 15, r0 = tid >> 4;
#pragma unroll
        for (int p = 0; p < 4; ++p) {
            const int c = r0 + p * 16;
            const float4 v = *(const float4*)(x + ((size_t)b * C_ + c0 + c) * T_ + t0 + f * 4);
            tile[c][f * 4 + 0] = f2b(v.x);
            tile[c][f * 4 + 1] = f2b(v.y);
            tile[c][f * 4 + 2] = f2b(v.z);
            tile[c][f * 4 + 3] = f2b(v.w);
        }
        __syncthreads();
#pragma unroll
        for (int p = 0; p < 4; ++p) {
            const int t = r0 + p * 16;
            ushort4 u;
            u.x = tile[f * 4 + 0][t];
            u.y = tile[f * 4 + 1][t];
            u.z = tile[f * 4 + 2][t];
            u.w = tile[f * 4 + 3][t];
            *(ushort4*)(xt + ((size_t)b * T_ + t0 + t) * C_ + c0 + f * 4) = u;
        }
    } else if (blk < 2048) {
        const int gid = (blk - 1024) * 256 + tid;
        const int s = gid >> 16;
        const int off = (gid & 65535) * 4;
        const float* W = (s == 0) ? Wq : (s == 1) ? Wk : (s == 2) ? Wv : Wo;
        const float4 v = *(const float4*)(W + off);
        ushort4 u;
        u.x = f2b(v.x); u.y = f2b(v.y); u.z = f2b(v.z); u.w = f2b(v.w);
        *(ushort4*)(Wh + ((size_t)s << 18) + off) = u;
    } else {
        const int idx = (blk - 2048) * 256 + tid;
        if (idx < 64 * 160) {
            const int d = idx / 160, rel = idx % 160;
            ervt[idx] = (rel < REL_) ? f2b(erv[rel * D_ + d]) : (u16)0;
        } else {
            const int j = idx - 64 * 160;
            if (j < REL_ * D_) erkb[j] = f2b(erk[j]);
        }
    }
}

// ---------------------------------------------------------------------------
// Kernel 1 v5: QKV projection, split q/k/v, t-tile 128, V epilogue transposed
// through LDS for coalesced vt stores. v4 BUG FIX: the gg epilogue loop was
// "#pragma unroll 1" while indexing acc[gg] -> runtime index forced the
// whole acc[2][4] f32x4 block to scratch (rule #20): VGPR 52, 293 MB scratch
// writes, +32 us steady. Now fully unrolled -> static indices, acc in VGPRs.
// grid = (T/128, H, 3*B), block 256, LDS 9.2 KB.
// ---------------------------------------------------------------------------
__global__ __launch_bounds__(256) void proj_mfma(
    const u16* __restrict__ xt, const u16* __restrict__ Wh,
    const float* __restrict__ bq, const float* __restrict__ bk, const float* __restrict__ bv,
    u16* __restrict__ qh, u16* __restrict__ kh, u16* __restrict__ vt)
{
    __shared__ u16 Wt[64][72];

    const int t0 = blockIdx.x * 128;
    const int h  = blockIdx.y;
    const int sel = blockIdx.z >> 3;
    const int b   = blockIdx.z & 7;
    const int tid = threadIdx.x, wave = tid >> 6, lane = tid & 63;
    const int quad = lane >> 4, l16 = lane & 15;

    const u16* Wbase = Wh + ((size_t)sel << 18) + ((size_t)(h * 64) << 9);
    const u16* A0 = xt + (((size_t)b * T_ + t0 + wave * 16 + l16) << 9);
    const u16* A1 = A0 + ((size_t)64 << 9);

    const int so = tid >> 2;
    const int sc = (tid & 3) * 16;
    const u16* wsrc = Wbase + ((size_t)so << 9) + sc;

    f32x4 acc[2][4];
#pragma unroll
    for (int gg = 0; gg < 2; ++gg)
#pragma unroll
        for (int nt = 0; nt < 4; ++nt) acc[gg][nt] = (f32x4){0.f, 0.f, 0.f, 0.f};

    uint4 wv0 = *(const uint4*)(wsrc);
    uint4 wv1 = *(const uint4*)(wsrc + 8);
#pragma unroll 1
    for (int i = 0; i < 8; ++i) {
        const int c0 = i * 64;
        __syncthreads();
        *(uint4*)&Wt[so][sc] = wv0;
        *(uint4*)&Wt[so][sc + 8] = wv1;
        __syncthreads();
        if (i < 7) {
            wv0 = *(const uint4*)(wsrc + c0 + 64);
            wv1 = *(const uint4*)(wsrc + c0 + 72);
        }
#pragma unroll
        for (int kk = 0; kk < 64; kk += 32) {
            const short8 af0 = *(const short8*)(A0 + c0 + kk + quad * 8);
            const short8 af1 = *(const short8*)(A1 + c0 + kk + quad * 8);
#pragma unroll
            for (int nt = 0; nt < 4; ++nt) {
                const short8 bf = *(const short8*)(&Wt[nt * 16 + l16][kk + quad * 8]);
                acc[0][nt] = __builtin_amdgcn_mfma_f32_16x16x32_bf16(af0, bf, acc[0][nt], 0, 0, 0);
                acc[1][nt] = __builtin_amdgcn_mfma_f32_16x16x32_bf16(af1, bf, acc[1][nt], 0, 0, 0);
            }
        }
    }

    const int bh = b * 8 + h;
    if (sel == 2) {
        // V: transpose through LDS (reuse Wt, two t-64 passes, fully
        // unrolled so acc indices stay compile-time), coalesced out
#pragma unroll
        for (int gg = 0; gg < 2; ++gg) {
            __syncthreads();
#pragma unroll
            for (int nt = 0; nt < 4; ++nt) {
                const int d = nt * 16 + l16;
                const float bo = bv[h * 64 + d];
#pragma unroll
                for (int rix = 0; rix < 4; ++rix) {
                    const int tl = wave * 16 + quad * 4 + rix;
                    Wt[d][tl] = f2b(acc[gg][nt][rix] + bo);
                }
            }
            __syncthreads();
            const int row = tid >> 2;         // 0..63 (d)
            const int seg = (tid & 3) * 16;   // 0,16,32,48 (t within 64)
            const uint4 v0 = *(const uint4*)&Wt[row][seg];
            const uint4 v1 = *(const uint4*)&Wt[row][seg + 8];
            u16* vdst = vt + (((size_t)bh * 64 + row) << 10) + t0 + gg * 64 + seg;
            *(uint4*)(vdst) = v0;
            *(uint4*)(vdst + 8) = v1;
        }
    } else {
        const float* bias = sel ? bk : bq;
        u16* dst = sel ? kh : qh;
#pragma unroll
        for (int nt = 0; nt < 4; ++nt) {
            const int d = nt * 16 + l16;
            const float bo = bias[h * 64 + d];
#pragma unroll
            for (int gg = 0; gg < 2; ++gg)
#pragma unroll
                for (int rix = 0; rix < 4; ++rix) {
                    const int t = t0 + gg * 64 + wave * 16 + quad * 4 + rix;
                    dst[(((size_t)bh * T_ + t) << 6) + d] = f2b(acc[gg][nt][rix] + bo);
                }
        }
    }
}

// ---------------------------------------------------------------------------
// Kernel 2: MFMA attention. v6 (kept): 32 q-rows, 256 thr / 4 waves,
// j-quarter per wave, exp2-domain math, cvt_pk packing, cross-iteration
// register prefetch of K/xmask/V. grid = 2048 (XCD-swizzled), block 256.
// LDS ~78 KB -> 2 blocks/CU.
// ---------------------------------------------------------------------------
__global__ __launch_bounds__(256, 2) void attn_kernel(
    const u16* __restrict__ qh, const u16* __restrict__ kh, const u16* __restrict__ vt,
    const u16* __restrict__ erkb, const u16* __restrict__ ervt,
    const float* __restrict__ xmask, u16* __restrict__ yf)
{
    __shared__ u16   Sb[32][1032];     // raw exp(score) bf16; later og staging
    __shared__ u16   sw[32][168];      // phase A: srel*log2e; phase B: wrel (raw)
    __shared__ float red[4][32][2];    // per-wave {sum, phi}
    __shared__ float invrow[32];

    const int gid = blockIdx.x;
    const int x8 = gid & 7, r5 = gid >> 3;
    const int bh = x8 + 8 * (r5 >> 5);
    const int i0 = (r5 & 31) * 32;
    const int b = bh >> 3, h = bh & 7;
    const int tid = threadIdx.x, wave = tid >> 6, lane = tid & 63;
    const int quad = lane >> 4, l16 = lane & 15;

    const float LOG2E = 1.4426950408889634f;
    const float SC    = 0.125f * 1.4426950408889634f;   // qk scale in exp2 domain

    // Q A-frags for both 16-row groups
    short8 qa[2][2];
#pragma unroll
    for (int g = 0; g < 2; ++g) {
        const u16* qrow = qh + (((size_t)bh * T_ + i0 + g * 16 + l16) << 6);
        qa[g][0] = *(const short8*)(qrow + quad * 8);
        qa[g][1] = *(const short8*)(qrow + 32 + quad * 8);
    }

    // ---- phase 1: srel via MFMA (stored pre-scaled by log2e) ----
    for (int tile = wave; tile < 9; tile += 4) {
        const int rel = tile * 16 + l16;
        const int rl = rel > 128 ? 128 : rel;
        const u16* ep = erkb + rl * 64 + quad * 8;
        const short8 b0 = *(const short8*)(ep);
        const short8 b1 = *(const short8*)(ep + 32);
#pragma unroll
        for (int g = 0; g < 2; ++g) {
            f32x4 m = {0.f, 0.f, 0.f, 0.f};
            m = __builtin_amdgcn_mfma_f32_16x16x32_bf16(qa[g][0], b0, m, 0, 0, 0);
            m = __builtin_amdgcn_mfma_f32_16x16x32_bf16(qa[g][1], b1, m, 0, 0, 0);
            if (rel < 129) {
#pragma unroll
                for (int rix = 0; rix < 4; ++rix)
                    sw[g * 16 + quad * 4 + rix][rel] = f2b(m[rix] * LOG2E);
            }
        }
    }
    __syncthreads();                                    // barrier 1

    // srel constants for fully-clamped tiles (exp2 domain)
    float slo_c[2][4], shi_c[2][4];
#pragma unroll
    for (int g = 0; g < 2; ++g)
#pragma unroll
        for (int rix = 0; rix < 4; ++rix) {
            const int row = g * 16 + quad * 4 + rix;
            slo_c[g][rix] = b2f(sw[row][0]);
            shi_c[g][rix] = b2f(sw[row][2 * K_]);
        }

    // ---- merged QK + exp + partial-PV over this wave's j-quarter ----
    float psum[2][4] = {{0.f,0.f,0.f,0.f},{0.f,0.f,0.f,0.f}};
    float phi [2][4] = {{0.f,0.f,0.f,0.f},{0.f,0.f,0.f,0.f}};
    f32x4 og[4][2];
#pragma unroll
    for (int s = 0; s < 4; ++s)
#pragma unroll
        for (int g = 0; g < 2; ++g) og[s][g] = (f32x4){0.f, 0.f, 0.f, 0.f};

    {
        const u16* kb = kh + ((size_t)bh << 16);
        const u16* vbase = vt + ((size_t)bh << 16);

        // ---- prefetch registers: K/mask one j-tile ahead, V one chunk ahead
        short8 kc0, kc1;
        float  xmc;
        {
            const u16* krow0 = kb + ((size_t)(wave * 256 + l16) << 6);
            kc0 = *(const short8*)(krow0 + quad * 8);
            kc1 = *(const short8*)(krow0 + 32 + quad * 8);
            xmc = xmask[b * T_ + wave * 256 + l16];
        }
        short8 vaf[4];
#pragma unroll
        for (int s = 0; s < 4; ++s)
            vaf[s] = *(const short8*)(vbase + ((size_t)(s * 16 + l16) << 10) + wave * 256 + quad * 8);

#pragma unroll 1
        for (int c = 0; c < 8; ++c) {
#pragma unroll
            for (int half = 0; half < 2; ++half) {
                const int ct = c * 2 + half;
                const int j0 = wave * 256 + ct * 16;
                const int j = j0 + l16;
                // rotate current, issue next-tile loads (clamped on last)
                const short8 kb0 = kc0, kb1 = kc1;
                const float xmv = xmc;
                {
                    const int jn = wave * 256 + ((ct < 15) ? ct + 1 : ct) * 16 + l16;
                    const u16* krown = kb + ((size_t)jn << 6);
                    kc0 = *(const short8*)(krown + quad * 8);
                    kc1 = *(const short8*)(krown + 32 + quad * 8);
                    xmc = xmask[b * T_ + jn];
                }
                // masked lanes clamp to -2e9 -> exp2 -> 0
                const float clampv = (xmv > 0.f) ? 43.280850f : -2.0e9f;
#pragma unroll
                for (int g = 0; g < 2; ++g) {
                    f32x4 acc = {0.f, 0.f, 0.f, 0.f};
                    acc = __builtin_amdgcn_mfma_f32_16x16x32_bf16(qa[g][0], kb0, acc, 0, 0, 0);
                    acc = __builtin_amdgcn_mfma_f32_16x16x32_bf16(qa[g][1], kb1, acc, 0, 0, 0);
                    const int dd = j0 - (i0 + g * 16);
                    const int ibase = i0 + g * 16 + quad * 4;
                    float ee[4];
                    if (dd <= -79) {
#pragma unroll
                        for (int rix = 0; rix < 4; ++rix)
                            ee[rix] = __builtin_amdgcn_exp2f(
                                fminf(fmaf(acc[rix], SC, slo_c[g][rix]), clampv));
                    } else if (dd >= 79) {
#pragma unroll
                        for (int rix = 0; rix < 4; ++rix)
                            ee[rix] = __builtin_amdgcn_exp2f(
                                fminf(fmaf(acc[rix], SC, shi_c[g][rix]), clampv));
                    } else {
                        const int relb = j - ibase + K_;
#pragma unroll
                        for (int rix = 0; rix < 4; ++rix) {
                            int idx = relb - rix;
                            idx = idx < 0 ? 0 : (idx > 2 * K_ ? 2 * K_ : idx);
                            const int row = g * 16 + quad * 4 + rix;
                            const float sr = b2f(sw[row][idx]);
                            ee[rix] = __builtin_amdgcn_exp2f(
                                fminf(fmaf(acc[rix], SC, sr), clampv));
                        }
                    }
                    // pack to bf16 pairs (RNE), store, accumulate rounded values
                    unsigned p01, p23;
                    asm("v_cvt_pk_bf16_f32 %0, %1, %2" : "=v"(p01) : "v"(ee[0]), "v"(ee[1]));
                    asm("v_cvt_pk_bf16_f32 %0, %1, %2" : "=v"(p23) : "v"(ee[2]), "v"(ee[3]));
                    const int r0 = g * 16 + quad * 4;
                    Sb[r0 + 0][j] = (u16)(p01 & 0xffffu);
                    Sb[r0 + 1][j] = (u16)(p01 >> 16);
                    Sb[r0 + 2][j] = (u16)(p23 & 0xffffu);
                    Sb[r0 + 3][j] = (u16)(p23 >> 16);
                    const float er0 = __uint_as_float(p01 << 16);
                    const float er1 = __uint_as_float(p01 & 0xffff0000u);
                    const float er2 = __uint_as_float(p23 << 16);
                    const float er3 = __uint_as_float(p23 & 0xffff0000u);
                    psum[g][0] += er0; psum[g][1] += er1;
                    psum[g][2] += er2; psum[g][3] += er3;
                    if (dd >= 79) {
                        phi[g][0] += er0; phi[g][1] += er1;
                        phi[g][2] += er2; phi[g][3] += er3;
                    } else if (dd > -79) {
                        phi[g][0] += (j - ibase >= 64) ? er0 : 0.f;
                        phi[g][1] += (j - ibase >= 65) ? er1 : 0.f;
                        phi[g][2] += (j - ibase >= 66) ? er2 : 0.f;
                        phi[g][3] += (j - ibase >= 67) ? er3 : 0.f;
                    }
                }
            }
            // partial PV for this 32-column chunk (same-wave data, no barrier)
            const int kc = wave * 256 + c * 32;
            const short8 pb0 = *(const short8*)(&Sb[l16][kc + quad * 8]);
            const short8 pb1 = *(const short8*)(&Sb[16 + l16][kc + quad * 8]);
            // prefetch V for next chunk (clamped on last)
            short8 vn[4];
            {
                const int kcn = wave * 256 + ((c < 7) ? c + 1 : c) * 32;
#pragma unroll
                for (int s = 0; s < 4; ++s)
                    vn[s] = *(const short8*)(vbase + ((size_t)(s * 16 + l16) << 10) + kcn + quad * 8);
            }
#pragma unroll
            for (int s = 0; s < 4; ++s) {
                og[s][0] = __builtin_amdgcn_mfma_f32_16x16x32_bf16(vaf[s], pb0, og[s][0], 0, 0, 0);
                og[s][1] = __builtin_amdgcn_mfma_f32_16x16x32_bf16(vaf[s], pb1, og[s][1], 0, 0, 0);
            }
#pragma unroll
            for (int s = 0; s < 4; ++s) vaf[s] = vn[s];
        }
#pragma unroll
        for (int m = 1; m < 16; m <<= 1)
#pragma unroll
            for (int g = 0; g < 2; ++g)
#pragma unroll
                for (int rix = 0; rix < 4; ++rix) {
                    psum[g][rix] += __shfl_xor(psum[g][rix], m);
                    phi[g][rix]  += __shfl_xor(phi[g][rix], m);
                }
        if (l16 == 0)
#pragma unroll
            for (int g = 0; g < 2; ++g)
#pragma unroll
                for (int rix = 0; rix < 4; ++rix) {
                    const int row = g * 16 + quad * 4 + rix;
                    red[wave][row][0] = psum[g][rix];
                    red[wave][row][1] = phi[g][rix];
                }
    }
    __syncthreads();                                    // barrier 2

    // ---- wrel (raw) from Sb; slo by complement; invrow ----
    {
        const int rr = tid >> 3;        // 0..31
        const int c0 = tid & 7;
        const float sumrow = red[0][rr][0] + red[1][rr][0] + red[2][rr][0] + red[3][rr][0];
        const float phirow = red[0][rr][1] + red[1][rr][1] + red[2][rr][1] + red[3][rr][1];
        float intsum = 0.f;
        for (int rel = c0; rel < 168; rel += 8) {
            if (rel == 0 || rel == 2 * K_) continue;
            u16 v = 0;
            if (rel < 2 * K_) {
                const int j = i0 + rr + rel - K_;
                if (j >= 0 && j < T_) v = Sb[rr][j];
                intsum += b2f(v);
            }
            sw[rr][rel] = v;
        }
        intsum += __shfl_xor(intsum, 1);
        intsum += __shfl_xor(intsum, 2);
        intsum += __shfl_xor(intsum, 4);
        if (c0 == 0) {
            sw[rr][2 * K_] = f2b(phirow);
            sw[rr][0]      = f2b(sumrow - intsum - phirow);
            invrow[rr]     = 1.0f / sumrow;
        }
    }
    __syncthreads();                                    // barrier 3

    // ---- stage og partials into LDS (aliased over dead Sb rows) ----
    float* fog = (float*)&Sb[0][0];                     // 4 waves x 2048 floats = 32 KB
#pragma unroll
    for (int s = 0; s < 4; ++s)
#pragma unroll
        for (int g = 0; g < 2; ++g)
            *(f32x4*)&fog[wave * 2048 + ((s * 2 + g) * 64 + lane) * 4] = og[s][g];
    __syncthreads();                                    // barrier 4

    // ---- owner wave (strip = wave): reduce 4 partials + rel-v MFMA; store ----
    {
        const int dh = wave * 16 + l16;
        const u16* ep = ervt + dh * 160;
        f32x4 accg[2];
#pragma unroll
        for (int g = 0; g < 2; ++g) {
            const int base = ((wave * 2 + g) * 64 + lane) * 4;
            f32x4 a0 = *(const f32x4*)&fog[base];
            f32x4 a1 = *(const f32x4*)&fog[2048 + base];
            f32x4 a2 = *(const f32x4*)&fog[4096 + base];
            f32x4 a3 = *(const f32x4*)&fog[6144 + base];
#pragma unroll
            for (int rix = 0; rix < 4; ++rix)
                accg[g][rix] = (a0[rix] + a1[rix]) + (a2[rix] + a3[rix]);
        }
#pragma unroll
        for (int kt = 0; kt < 5; ++kt) {
            const short8 af = *(const short8*)(ep + kt * 32 + quad * 8);
            const short8 p0 = *(const short8*)(&sw[l16][kt * 32 + quad * 8]);
            const short8 p1 = *(const short8*)(&sw[16 + l16][kt * 32 + quad * 8]);
            accg[0] = __builtin_amdgcn_mfma_f32_16x16x32_bf16(af, p0, accg[0], 0, 0, 0);
            accg[1] = __builtin_amdgcn_mfma_f32_16x16x32_bf16(af, p1, accg[1], 0, 0, 0);
        }
        const int dbase = (h << 6) + wave * 16 + quad * 4;
#pragma unroll
        for (int g = 0; g < 2; ++g) {
            const float iv = invrow[g * 16 + l16];
            ushort4 u;
            u.x = f2b(accg[g][0] * iv); u.y = f2b(accg[g][1] * iv);
            u.z = f2b(accg[g][2] * iv); u.w = f2b(accg[g][3] * iv);
            *(ushort4*)(yf + (((size_t)b * T_ + i0 + g * 16 + l16) << 9) + dbase) = u;
        }
    }
}

// ---------------------------------------------------------------------------
// Kernel 3: output projection via MFMA (R8 64-tile). yf tile staged in LDS.
// grid = (C/64, B*T/64), block 256.
// ---------------------------------------------------------------------------
__global__ __launch_bounds__(256) void outproj_mfma(
    const u16* __restrict__ yf, const u16* __restrict__ Woh, const float* __restrict__ bo,
    const float* __restrict__ xmask, float* __restrict__ out)
{
    __shared__ u16 Yt[64][72];

    const int o0 = blockIdx.x * 64;
    const int b  = blockIdx.y >> 4;
    const int t0 = (blockIdx.y & 15) * 64;
    const int tid = threadIdx.x, wave = tid >> 6, lane = tid & 63;
    const int quad = lane >> 4, l16 = lane & 15;

    const u16* A = Woh + ((size_t)(o0 + wave * 16 + l16) << 9);

    const int so = tid >> 2;
    const int sc = (tid & 3) * 16;
    const u16* ysrc = yf + (((size_t)b * T_ + t0 + so) << 9) + sc;

    f32x4 acc[4] = {{0.f,0.f,0.f,0.f},{0.f,0.f,0.f,0.f},{0.f,0.f,0.f,0.f},{0.f,0.f,0.f,0.f}};

    uint4 wv0 = *(const uint4*)(ysrc);
    uint4 wv1 = *(const uint4*)(ysrc + 8);
#pragma unroll 1
    for (int i = 0; i < 8; ++i) {
        const int c0 = i * 64;
        __syncthreads();
        *(uint4*)&Yt[so][sc] = wv0;
        *(uint4*)&Yt[so][sc + 8] = wv1;
        __syncthreads();
        if (i < 7) {
            wv0 = *(const uint4*)(ysrc + c0 + 64);
            wv1 = *(const uint4*)(ysrc + c0 + 72);
        }
#pragma unroll
        for (int kk = 0; kk < 64; kk += 32) {
            const short8 af = *(const short8*)(A + c0 + kk + quad * 8);
#pragma unroll
            for (int nt = 0; nt < 4; ++nt) {
                const short8 bf = *(const short8*)(&Yt[nt * 16 + l16][kk + quad * 8]);
                acc[nt] = __builtin_amdgcn_mfma_f32_16x16x32_bf16(af, bf, acc[nt], 0, 0, 0);
            }
        }
    }

#pragma unroll
    for (int nt = 0; nt < 4; ++nt) {
        const int t = t0 + nt * 16 + l16;
        const float xmv = xmask[b * T_ + t];
#pragma unroll
        for (int rix = 0; rix < 4; ++rix) {
            const int o = o0 + wave * 16 + quad * 4 + rix;
            out[((size_t)b * C_ + o) * T_ + t] = (acc[nt][rix] + bo[o]) * xmv;
        }
    }
}

// ---------------------------------------------------------------------------
extern "C" void kernel_launch(void* const* d_in, const int* in_sizes, int n_in,
                              void* d_out, int out_size, void* d_ws, size_t ws_size,
                              hipStream_t stream) {
    const float* x     = (const float*)d_in[0];
    const float* xmask = (const float*)d_in[1];
    const float* Wq    = (const float*)d_in[2];
    const float* bq    = (const float*)d_in[3];
    const float* Wk    = (const float*)d_in[4];
    const float* bk    = (const float*)d_in[5];
    const float* Wv    = (const float*)d_in[6];
    const float* bv    = (const float*)d_in[7];
    const float* Wo    = (const float*)d_in[8];
    const float* bo    = (const float*)d_in[9];
    const float* erk   = (const float*)d_in[10];
    const float* erv   = (const float*)d_in[11];

    // workspace (bf16):
    //   xt [B,T,C]    @ 0         (8 MB)
    //   Wh [4,C,C]    @ 8 MB      (2 MB)
    //   qh [B,H,T,D]  @ 10 MB     (8 MB)
    //   kh            @ 18 MB     (8 MB)
    //   vt [B,H,D,T]  @ 26 MB     (8 MB)
    //   yf [B,T,C]    @ 34 MB     (8 MB)
    //   ervt [64,160] @ 44040192  (20480 B)
    //   erkb [129,64] @ 44060672  (16512 B)
    const size_t need = 44077184;
    if (ws_size < need) return;
    u16* xt   = (u16*)d_ws;
    u16* Wh   = (u16*)((char*)d_ws + 8388608);
    u16* qh   = (u16*)((char*)d_ws + 10485760);
    u16* kh   = (u16*)((char*)d_ws + 18874368);
    u16* vt   = (u16*)((char*)d_ws + 27262976);
    u16* yf   = (u16*)((char*)d_ws + 35651584);
    u16* ervt = (u16*)((char*)d_ws + 44040192);
    u16* erkb = (u16*)((char*)d_ws + 44060672);
    float* out = (float*)d_out;

    cast_all_kernel<<<dim3(2121), 256, 0, stream>>>(
        x, Wq, Wk, Wv, Wo, erk, erv, xt, Wh, ervt, erkb);
    proj_mfma<<<dim3(T_ / 128, H_, 3 * B_), 256, 0, stream>>>(
        xt, Wh, bq, bk, bv, qh, kh, vt);
    attn_kernel<<<dim3(2048), 256, 0, stream>>>(
        qh, kh, vt, erkb, ervt, xmask, yf);
    outproj_mfma<<<dim3(C_ / 64, B_ * (T_ / 64)), 256, 0, stream>>>(
        yf, Wh + ((size_t)3 << 18), bo, xmask, out);
}

// Round 10
// 214.427 us; speedup vs baseline: 1.2630x; 1.0512x over previous
//
#include <hip/hip_runtime.h>

// (B,C,T)=(8,512,1024), H=8, D=64, K=64, REL=129. I/O fp32; internal bf16.
#define B_   8
#define C_   512
#define T_   1024
#define H_   8
#define D_   64
#define K_   64
#define REL_ 129

typedef unsigned short u16;
typedef __attribute__((ext_vector_type(8))) short short8;   // 8 bf16 (4 VGPRs)
typedef __attribute__((ext_vector_type(4))) float f32x4;

__device__ __forceinline__ float b2f(u16 u) {
    return __uint_as_float(((unsigned)u) << 16);
}
__device__ __forceinline__ u16 f2b(float f) {
    unsigned x = __float_as_uint(f);
    x += 0x7fffu + ((x >> 16) & 1u);   // RNE
    return (u16)(x >> 16);
}

// ---------------------------------------------------------------------------
// Kernel 0: all input casts in one launch.
// ---------------------------------------------------------------------------
__global__ __launch_bounds__(256) void cast_all_kernel(
    const float* __restrict__ x,
    const float* __restrict__ Wq, const float* __restrict__ Wk,
    const float* __restrict__ Wv, const float* __restrict__ Wo,
    const float* __restrict__ erk, const float* __restrict__ erv,
    u16* __restrict__ xt, u16* __restrict__ Wh,
    u16* __restrict__ ervt, u16* __restrict__ erkb)
{
    __shared__ u16 tile[64][72];
    const int blk = blockIdx.x;
    const int tid = threadIdx.x;
    if (blk < 1024) {
        const int t0 = (blk & 15) * 64, c0 = ((blk >> 4) & 7) * 64, b = blk >> 7;
        const int f = tid & 15, r0 = tid >> 4;
#pragma unroll
        for (int p = 0; p < 4; ++p) {
            const int c = r0 + p * 16;
            const float4 v = *(const float4*)(x + ((size_t)b * C_ + c0 + c) * T_ + t0 + f * 4);
            tile[c][f * 4 + 0] = f2b(v.x);
            tile[c][f * 4 + 1] = f2b(v.y);
            tile[c][f * 4 + 2] = f2b(v.z);
            tile[c][f * 4 + 3] = f2b(v.w);
        }
        __syncthreads();
#pragma unroll
        for (int p = 0; p < 4; ++p) {
            const int t = r0 + p * 16;
            ushort4 u;
            u.x = tile[f * 4 + 0][t];
            u.y = tile[f * 4 + 1][t];
            u.z = tile[f * 4 + 2][t];
            u.w = tile[f * 4 + 3][t];
            *(ushort4*)(xt + ((size_t)b * T_ + t0 + t) * C_ + c0 + f * 4) = u;
        }
    } else if (blk < 2048) {
        const int gid = (blk - 1024) * 256 + tid;
        const int s = gid >> 16;
        const int off = (gid & 65535) * 4;
        const float* W = (s == 0) ? Wq : (s == 1) ? Wk : (s == 2) ? Wv : Wo;
        const float4 v = *(const float4*)(W + off);
        ushort4 u;
        u.x = f2b(v.x); u.y = f2b(v.y); u.z = f2b(v.z); u.w = f2b(v.w);
        *(ushort4*)(Wh + ((size_t)s << 18) + off) = u;
    } else {
        const int idx = (blk - 2048) * 256 + tid;
        if (idx < 64 * 160) {
            const int d = idx / 160, rel = idx % 160;
            ervt[idx] = (rel < REL_) ? f2b(erv[rel * D_ + d]) : (u16)0;
        } else {
            const int j = idx - 64 * 160;
            if (j < REL_ * D_) erkb[j] = f2b(erk[j]);
        }
    }
}

// ---------------------------------------------------------------------------
// Kernel 1 v5: QKV projection, split q/k/v, t-tile 128, V epilogue transposed
// through LDS (fully unrolled gg -> static acc indices; rule #20).
// grid = (T/128, H, 3*B), block 256, LDS 9.2 KB.
// ---------------------------------------------------------------------------
__global__ __launch_bounds__(256) void proj_mfma(
    const u16* __restrict__ xt, const u16* __restrict__ Wh,
    const float* __restrict__ bq, const float* __restrict__ bk, const float* __restrict__ bv,
    u16* __restrict__ qh, u16* __restrict__ kh, u16* __restrict__ vt)
{
    __shared__ u16 Wt[64][72];

    const int t0 = blockIdx.x * 128;
    const int h  = blockIdx.y;
    const int sel = blockIdx.z >> 3;
    const int b   = blockIdx.z & 7;
    const int tid = threadIdx.x, wave = tid >> 6, lane = tid & 63;
    const int quad = lane >> 4, l16 = lane & 15;

    const u16* Wbase = Wh + ((size_t)sel << 18) + ((size_t)(h * 64) << 9);
    const u16* A0 = xt + (((size_t)b * T_ + t0 + wave * 16 + l16) << 9);
    const u16* A1 = A0 + ((size_t)64 << 9);

    const int so = tid >> 2;
    const int sc = (tid & 3) * 16;
    const u16* wsrc = Wbase + ((size_t)so << 9) + sc;

    f32x4 acc[2][4];
#pragma unroll
    for (int gg = 0; gg < 2; ++gg)
#pragma unroll
        for (int nt = 0; nt < 4; ++nt) acc[gg][nt] = (f32x4){0.f, 0.f, 0.f, 0.f};

    uint4 wv0 = *(const uint4*)(wsrc);
    uint4 wv1 = *(const uint4*)(wsrc + 8);
#pragma unroll 1
    for (int i = 0; i < 8; ++i) {
        const int c0 = i * 64;
        __syncthreads();
        *(uint4*)&Wt[so][sc] = wv0;
        *(uint4*)&Wt[so][sc + 8] = wv1;
        __syncthreads();
        if (i < 7) {
            wv0 = *(const uint4*)(wsrc + c0 + 64);
            wv1 = *(const uint4*)(wsrc + c0 + 72);
        }
#pragma unroll
        for (int kk = 0; kk < 64; kk += 32) {
            const short8 af0 = *(const short8*)(A0 + c0 + kk + quad * 8);
            const short8 af1 = *(const short8*)(A1 + c0 + kk + quad * 8);
#pragma unroll
            for (int nt = 0; nt < 4; ++nt) {
                const short8 bf = *(const short8*)(&Wt[nt * 16 + l16][kk + quad * 8]);
                acc[0][nt] = __builtin_amdgcn_mfma_f32_16x16x32_bf16(af0, bf, acc[0][nt], 0, 0, 0);
                acc[1][nt] = __builtin_amdgcn_mfma_f32_16x16x32_bf16(af1, bf, acc[1][nt], 0, 0, 0);
            }
        }
    }

    const int bh = b * 8 + h;
    if (sel == 2) {
#pragma unroll
        for (int gg = 0; gg < 2; ++gg) {
            __syncthreads();
#pragma unroll
            for (int nt = 0; nt < 4; ++nt) {
                const int d = nt * 16 + l16;
                const float bo = bv[h * 64 + d];
#pragma unroll
                for (int rix = 0; rix < 4; ++rix) {
                    const int tl = wave * 16 + quad * 4 + rix;
                    Wt[d][tl] = f2b(acc[gg][nt][rix] + bo);
                }
            }
            __syncthreads();
            const int row = tid >> 2;
            const int seg = (tid & 3) * 16;
            const uint4 v0 = *(const uint4*)&Wt[row][seg];
            const uint4 v1 = *(const uint4*)&Wt[row][seg + 8];
            u16* vdst = vt + (((size_t)bh * 64 + row) << 10) + t0 + gg * 64 + seg;
            *(uint4*)(vdst) = v0;
            *(uint4*)(vdst + 8) = v1;
        }
    } else {
        const float* bias = sel ? bk : bq;
        u16* dst = sel ? kh : qh;
#pragma unroll
        for (int nt = 0; nt < 4; ++nt) {
            const int d = nt * 16 + l16;
            const float bo = bias[h * 64 + d];
#pragma unroll
            for (int gg = 0; gg < 2; ++gg)
#pragma unroll
                for (int rix = 0; rix < 4; ++rix) {
                    const int t = t0 + gg * 64 + wave * 16 + quad * 4 + rix;
                    dst[(((size_t)bh * T_ + t) << 6) + d] = f2b(acc[gg][nt][rix] + bo);
                }
        }
    }
}

// ---------------------------------------------------------------------------
// Kernel 2 v11: MFMA attention, LDS DIET for 4 blocks/CU. Same 32-row
// decomposition and math as v6 (best), but the 66 KB full-P buffer Sb is
// replaced by its three actual uses:
//   chunkbuf[4][32][40]: transient per-wave 32-col P chunk (PV B-operand)
//   bandbuf[32][136]   : persistent diagonal band rel 1..127 (zero-init)
//   ogbuf[32][68] f32  : single reduced O buffer, 4-pass sequential accum
// LDS 39.5 KB -> 4 blocks/CU = 4 waves/SIMD (2x v6 TLP, per-block work
// unchanged — v5's failure was halved work, not occupancy). VGPR ~v6 (92);
// launch_bounds(256,3) caps 170 (no spill risk), occupancy LDS-limited.
// grid = 2048 (XCD-swizzled), block 256.
// ---------------------------------------------------------------------------
__global__ __launch_bounds__(256, 3) void attn_kernel(
    const u16* __restrict__ qh, const u16* __restrict__ kh, const u16* __restrict__ vt,
    const u16* __restrict__ erkb, const u16* __restrict__ ervt,
    const float* __restrict__ xmask, u16* __restrict__ yf)
{
    __shared__ u16   sw[32][168];        // phase A: srel*log2e; phase B: wrel
    __shared__ u16   bandbuf[32][136];   // raw exp at rel 1..127 (zero-init)
    __shared__ u16   chunkbuf[4][32][40];// per-wave transient P chunk
    __shared__ float ogbuf[32][68];      // reduced O partials [t][d]
    __shared__ float red[4][32][2];      // per-wave {sum, phi}
    __shared__ float invrow[32];

    const int gid = blockIdx.x;
    const int x8 = gid & 7, r5 = gid >> 3;
    const int bh = x8 + 8 * (r5 >> 5);
    const int i0 = (r5 & 31) * 32;
    const int b = bh >> 3, h = bh & 7;
    const int tid = threadIdx.x, wave = tid >> 6, lane = tid & 63;
    const int quad = lane >> 4, l16 = lane & 15;

    const float LOG2E = 1.4426950408889634f;
    const float SC    = 0.125f * 1.4426950408889634f;   // qk scale in exp2 domain

    // zero-init bandbuf (unwritten slots must read as 0)
    {
        unsigned* bb = (unsigned*)&bandbuf[0][0];
#pragma unroll 1
        for (int k2 = tid; k2 < 32 * 68; k2 += 256) bb[k2] = 0u;
    }

    // Q A-frags for both 16-row groups
    short8 qa[2][2];
#pragma unroll
    for (int g = 0; g < 2; ++g) {
        const u16* qrow = qh + (((size_t)bh * T_ + i0 + g * 16 + l16) << 6);
        qa[g][0] = *(const short8*)(qrow + quad * 8);
        qa[g][1] = *(const short8*)(qrow + 32 + quad * 8);
    }

    // ---- phase 1: srel via MFMA (stored pre-scaled by log2e) ----
    for (int tile = wave; tile < 9; tile += 4) {
        const int rel = tile * 16 + l16;
        const int rl = rel > 128 ? 128 : rel;
        const u16* ep = erkb + rl * 64 + quad * 8;
        const short8 b0 = *(const short8*)(ep);
        const short8 b1 = *(const short8*)(ep + 32);
#pragma unroll
        for (int g = 0; g < 2; ++g) {
            f32x4 m = {0.f, 0.f, 0.f, 0.f};
            m = __builtin_amdgcn_mfma_f32_16x16x32_bf16(qa[g][0], b0, m, 0, 0, 0);
            m = __builtin_amdgcn_mfma_f32_16x16x32_bf16(qa[g][1], b1, m, 0, 0, 0);
            if (rel < 129) {
#pragma unroll
                for (int rix = 0; rix < 4; ++rix)
                    sw[g * 16 + quad * 4 + rix][rel] = f2b(m[rix] * LOG2E);
            }
        }
    }
    __syncthreads();                                    // barrier 1

    // srel constants for fully-clamped tiles (exp2 domain)
    float slo_c[2][4], shi_c[2][4];
#pragma unroll
    for (int g = 0; g < 2; ++g)
#pragma unroll
        for (int rix = 0; rix < 4; ++rix) {
            const int row = g * 16 + quad * 4 + rix;
            slo_c[g][rix] = b2f(sw[row][0]);
            shi_c[g][rix] = b2f(sw[row][2 * K_]);
        }

    // ---- merged QK + exp + partial-PV over this wave's j-quarter ----
    float psum[2][4] = {{0.f,0.f,0.f,0.f},{0.f,0.f,0.f,0.f}};
    float phi [2][4] = {{0.f,0.f,0.f,0.f},{0.f,0.f,0.f,0.f}};
    f32x4 og[4][2];
#pragma unroll
    for (int s = 0; s < 4; ++s)
#pragma unroll
        for (int g = 0; g < 2; ++g) og[s][g] = (f32x4){0.f, 0.f, 0.f, 0.f};

    {
        const u16* kb = kh + ((size_t)bh << 16);
        const u16* vbase = vt + ((size_t)bh << 16);

        // prefetch registers: K/mask one j-tile ahead, V one chunk ahead
        short8 kc0, kc1;
        float  xmc;
        {
            const u16* krow0 = kb + ((size_t)(wave * 256 + l16) << 6);
            kc0 = *(const short8*)(krow0 + quad * 8);
            kc1 = *(const short8*)(krow0 + 32 + quad * 8);
            xmc = xmask[b * T_ + wave * 256 + l16];
        }
        short8 vaf[4];
#pragma unroll
        for (int s = 0; s < 4; ++s)
            vaf[s] = *(const short8*)(vbase + ((size_t)(s * 16 + l16) << 10) + wave * 256 + quad * 8);

#pragma unroll 1
        for (int c = 0; c < 8; ++c) {
#pragma unroll
            for (int half = 0; half < 2; ++half) {
                const int ct = c * 2 + half;
                const int j0 = wave * 256 + ct * 16;
                const int j = j0 + l16;
                const short8 kb0 = kc0, kb1 = kc1;
                const float xmv = xmc;
                {
                    const int jn = wave * 256 + ((ct < 15) ? ct + 1 : ct) * 16 + l16;
                    const u16* krown = kb + ((size_t)jn << 6);
                    kc0 = *(const short8*)(krown + quad * 8);
                    kc1 = *(const short8*)(krown + 32 + quad * 8);
                    xmc = xmask[b * T_ + jn];
                }
                const float clampv = (xmv > 0.f) ? 43.280850f : -2.0e9f;
#pragma unroll
                for (int g = 0; g < 2; ++g) {
                    f32x4 acc = {0.f, 0.f, 0.f, 0.f};
                    acc = __builtin_amdgcn_mfma_f32_16x16x32_bf16(qa[g][0], kb0, acc, 0, 0, 0);
                    acc = __builtin_amdgcn_mfma_f32_16x16x32_bf16(qa[g][1], kb1, acc, 0, 0, 0);
                    const int dd = j0 - (i0 + g * 16);
                    const int ibase = i0 + g * 16 + quad * 4;
                    const int relb = j - ibase + K_;
                    const bool interior = (dd > -79) && (dd < 79);
                    float ee[4];
                    if (dd <= -79) {
#pragma unroll
                        for (int rix = 0; rix < 4; ++rix)
                            ee[rix] = __builtin_amdgcn_exp2f(
                                fminf(fmaf(acc[rix], SC, slo_c[g][rix]), clampv));
                    } else if (dd >= 79) {
#pragma unroll
                        for (int rix = 0; rix < 4; ++rix)
                            ee[rix] = __builtin_amdgcn_exp2f(
                                fminf(fmaf(acc[rix], SC, shi_c[g][rix]), clampv));
                    } else {
#pragma unroll
                        for (int rix = 0; rix < 4; ++rix) {
                            int idx = relb - rix;
                            idx = idx < 0 ? 0 : (idx > 2 * K_ ? 2 * K_ : idx);
                            const int row = g * 16 + quad * 4 + rix;
                            const float sr = b2f(sw[row][idx]);
                            ee[rix] = __builtin_amdgcn_exp2f(
                                fminf(fmaf(acc[rix], SC, sr), clampv));
                        }
                    }
                    // pack to bf16 pairs (RNE)
                    unsigned p01, p23;
                    asm("v_cvt_pk_bf16_f32 %0, %1, %2" : "=v"(p01) : "v"(ee[0]), "v"(ee[1]));
                    asm("v_cvt_pk_bf16_f32 %0, %1, %2" : "=v"(p23) : "v"(ee[2]), "v"(ee[3]));
                    const int r0 = g * 16 + quad * 4;
                    const int ccol = half * 16 + l16;
                    const u16 pv0 = (u16)(p01 & 0xffffu);
                    const u16 pv1 = (u16)(p01 >> 16);
                    const u16 pv2 = (u16)(p23 & 0xffffu);
                    const u16 pv3 = (u16)(p23 >> 16);
                    chunkbuf[wave][r0 + 0][ccol] = pv0;
                    chunkbuf[wave][r0 + 1][ccol] = pv1;
                    chunkbuf[wave][r0 + 2][ccol] = pv2;
                    chunkbuf[wave][r0 + 3][ccol] = pv3;
                    if (interior) {
                        // band slots rel in [1,127] for rows r0+rix
                        if ((unsigned)(relb - 1) < 127u) bandbuf[r0 + 0][relb]     = pv0;
                        if ((unsigned)(relb - 2) < 127u) bandbuf[r0 + 1][relb - 1] = pv1;
                        if ((unsigned)(relb - 3) < 127u) bandbuf[r0 + 2][relb - 2] = pv2;
                        if ((unsigned)(relb - 4) < 127u) bandbuf[r0 + 3][relb - 3] = pv3;
                    }
                    const float er0 = __uint_as_float(p01 << 16);
                    const float er1 = __uint_as_float(p01 & 0xffff0000u);
                    const float er2 = __uint_as_float(p23 << 16);
                    const float er3 = __uint_as_float(p23 & 0xffff0000u);
                    psum[g][0] += er0; psum[g][1] += er1;
                    psum[g][2] += er2; psum[g][3] += er3;
                    if (dd >= 79) {
                        phi[g][0] += er0; phi[g][1] += er1;
                        phi[g][2] += er2; phi[g][3] += er3;
                    } else if (dd > -79) {
                        phi[g][0] += (j - ibase >= 64) ? er0 : 0.f;
                        phi[g][1] += (j - ibase >= 65) ? er1 : 0.f;
                        phi[g][2] += (j - ibase >= 66) ? er2 : 0.f;
                        phi[g][3] += (j - ibase >= 67) ? er3 : 0.f;
                    }
                }
            }
            // partial PV for this 32-column chunk (same-wave data, no barrier)
            const short8 pb0 = *(const short8*)(&chunkbuf[wave][l16][quad * 8]);
            const short8 pb1 = *(const short8*)(&chunkbuf[wave][16 + l16][quad * 8]);
            // prefetch V for next chunk (clamped on last)
            short8 vn[4];
            {
                const int kcn = wave * 256 + ((c < 7) ? c + 1 : c) * 32;
#pragma unroll
                for (int s = 0; s < 4; ++s)
                    vn[s] = *(const short8*)(vbase + ((size_t)(s * 16 + l16) << 10) + kcn + quad * 8);
            }
#pragma unroll
            for (int s = 0; s < 4; ++s) {
                og[s][0] = __builtin_amdgcn_mfma_f32_16x16x32_bf16(vaf[s], pb0, og[s][0], 0, 0, 0);
                og[s][1] = __builtin_amdgcn_mfma_f32_16x16x32_bf16(vaf[s], pb1, og[s][1], 0, 0, 0);
            }
#pragma unroll
            for (int s = 0; s < 4; ++s) vaf[s] = vn[s];
        }
#pragma unroll
        for (int m = 1; m < 16; m <<= 1)
#pragma unroll
            for (int g = 0; g < 2; ++g)
#pragma unroll
                for (int rix = 0; rix < 4; ++rix) {
                    psum[g][rix] += __shfl_xor(psum[g][rix], m);
                    phi[g][rix]  += __shfl_xor(phi[g][rix], m);
                }
        if (l16 == 0)
#pragma unroll
            for (int g = 0; g < 2; ++g)
#pragma unroll
                for (int rix = 0; rix < 4; ++rix) {
                    const int row = g * 16 + quad * 4 + rix;
                    red[wave][row][0] = psum[g][rix];
                    red[wave][row][1] = phi[g][rix];
                }
    }
    __syncthreads();                                    // barrier 2

    // ---- wrel (raw) from bandbuf; slo by complement; invrow ----
    {
        const int rr = tid >> 3;        // 0..31
        const int c0 = tid & 7;
        const float sumrow = red[0][rr][0] + red[1][rr][0] + red[2][rr][0] + red[3][rr][0];
        const float phirow = red[0][rr][1] + red[1][rr][1] + red[2][rr][1] + red[3][rr][1];
        float intsum = 0.f;
        for (int rel = c0; rel < 168; rel += 8) {
            if (rel == 0 || rel == 2 * K_) continue;
            u16 v = 0;
            if (rel < 2 * K_) {
                v = bandbuf[rr][rel];
                intsum += b2f(v);
            }
            sw[rr][rel] = v;
        }
        intsum += __shfl_xor(intsum, 1);
        intsum += __shfl_xor(intsum, 2);
        intsum += __shfl_xor(intsum, 4);
        if (c0 == 0) {
            sw[rr][2 * K_] = f2b(phirow);
            sw[rr][0]      = f2b(sumrow - intsum - phirow);
            invrow[rr]     = 1.0f / sumrow;
        }
    }
    __syncthreads();                                    // barrier 3

    // ---- accumulate og partials into ogbuf (4 sequential passes) ----
#pragma unroll
    for (int w = 0; w < 4; ++w) {
        if (wave == w) {
            if (w == 0) {
#pragma unroll
                for (int s = 0; s < 4; ++s)
#pragma unroll
                    for (int g = 0; g < 2; ++g)
                        *(f32x4*)&ogbuf[g * 16 + l16][s * 16 + quad * 4] = og[s][g];
            } else {
#pragma unroll
                for (int s = 0; s < 4; ++s)
#pragma unroll
                    for (int g = 0; g < 2; ++g) {
                        f32x4 cur = *(const f32x4*)&ogbuf[g * 16 + l16][s * 16 + quad * 4];
                        cur = cur + og[s][g];
                        *(f32x4*)&ogbuf[g * 16 + l16][s * 16 + quad * 4] = cur;
                    }
            }
        }
        __syncthreads();                                // barriers 4..7
    }

    // ---- owner wave (strip = wave): read reduced og + rel-v MFMA; store ----
    {
        const int dh = wave * 16 + l16;
        const u16* ep = ervt + dh * 160;
        f32x4 accg[2];
#pragma unroll
        for (int g = 0; g < 2; ++g)
            accg[g] = *(const f32x4*)&ogbuf[g * 16 + l16][wave * 16 + quad * 4];
#pragma unroll
        for (int kt = 0; kt < 5; ++kt) {
            const short8 af = *(const short8*)(ep + kt * 32 + quad * 8);
            const short8 p0 = *(const short8*)(&sw[l16][kt * 32 + quad * 8]);
            const short8 p1 = *(const short8*)(&sw[16 + l16][kt * 32 + quad * 8]);
            accg[0] = __builtin_amdgcn_mfma_f32_16x16x32_bf16(af, p0, accg[0], 0, 0, 0);
            accg[1] = __builtin_amdgcn_mfma_f32_16x16x32_bf16(af, p1, accg[1], 0, 0, 0);
        }
        const int dbase = (h << 6) + wave * 16 + quad * 4;
#pragma unroll
        for (int g = 0; g < 2; ++g) {
            const float iv = invrow[g * 16 + l16];
            ushort4 u;
            u.x = f2b(accg[g][0] * iv); u.y = f2b(accg[g][1] * iv);
            u.z = f2b(accg[g][2] * iv); u.w = f2b(accg[g][3] * iv);
            *(ushort4*)(yf + (((size_t)b * T_ + i0 + g * 16 + l16) << 9) + dbase) = u;
        }
    }
}

// ---------------------------------------------------------------------------
// Kernel 3: output projection via MFMA (R8 64-tile). yf tile staged in LDS.
// grid = (C/64, B*T/64), block 256.
// ---------------------------------------------------------------------------
__global__ __launch_bounds__(256) void outproj_mfma(
    const u16* __restrict__ yf, const u16* __restrict__ Woh, const float* __restrict__ bo,
    const float* __restrict__ xmask, float* __restrict__ out)
{
    __shared__ u16 Yt[64][72];

    const int o0 = blockIdx.x * 64;
    const int b  = blockIdx.y >> 4;
    const int t0 = (blockIdx.y & 15) * 64;
    const int tid = threadIdx.x, wave = tid >> 6, lane = tid & 63;
    const int quad = lane >> 4, l16 = lane & 15;

    const u16* A = Woh + ((size_t)(o0 + wave * 16 + l16) << 9);

    const int so = tid >> 2;
    const int sc = (tid & 3) * 16;
    const u16* ysrc = yf + (((size_t)b * T_ + t0 + so) << 9) + sc;

    f32x4 acc[4] = {{0.f,0.f,0.f,0.f},{0.f,0.f,0.f,0.f},{0.f,0.f,0.f,0.f},{0.f,0.f,0.f,0.f}};

    uint4 wv0 = *(const uint4*)(ysrc);
    uint4 wv1 = *(const uint4*)(ysrc + 8);
#pragma unroll 1
    for (int i = 0; i < 8; ++i) {
        const int c0 = i * 64;
        __syncthreads();
        *(uint4*)&Yt[so][sc] = wv0;
        *(uint4*)&Yt[so][sc + 8] = wv1;
        __syncthreads();
        if (i < 7) {
            wv0 = *(const uint4*)(ysrc + c0 + 64);
            wv1 = *(const uint4*)(ysrc + c0 + 72);
        }
#pragma unroll
        for (int kk = 0; kk < 64; kk += 32) {
            const short8 af = *(const short8*)(A + c0 + kk + quad * 8);
#pragma unroll
            for (int nt = 0; nt < 4; ++nt) {
                const short8 bf = *(const short8*)(&Yt[nt * 16 + l16][kk + quad * 8]);
                acc[nt] = __builtin_amdgcn_mfma_f32_16x16x32_bf16(af, bf, acc[nt], 0, 0, 0);
            }
        }
    }

#pragma unroll
    for (int nt = 0; nt < 4; ++nt) {
        const int t = t0 + nt * 16 + l16;
        const float xmv = xmask[b * T_ + t];
#pragma unroll
        for (int rix = 0; rix < 4; ++rix) {
            const int o = o0 + wave * 16 + quad * 4 + rix;
            out[((size_t)b * C_ + o) * T_ + t] = (acc[nt][rix] + bo[o]) * xmv;
        }
    }
}

// ---------------------------------------------------------------------------
extern "C" void kernel_launch(void* const* d_in, const int* in_sizes, int n_in,
                              void* d_out, int out_size, void* d_ws, size_t ws_size,
                              hipStream_t stream) {
    const float* x     = (const float*)d_in[0];
    const float* xmask = (const float*)d_in[1];
    const float* Wq    = (const float*)d_in[2];
    const float* bq    = (const float*)d_in[3];
    const float* Wk    = (const float*)d_in[4];
    const float* bk    = (const float*)d_in[5];
    const float* Wv    = (const float*)d_in[6];
    const float* bv    = (const float*)d_in[7];
    const float* Wo    = (const float*)d_in[8];
    const float* bo    = (const float*)d_in[9];
    const float* erk   = (const float*)d_in[10];
    const float* erv   = (const float*)d_in[11];

    // workspace (bf16):
    //   xt [B,T,C]    @ 0         (8 MB)
    //   Wh [4,C,C]    @ 8 MB      (2 MB)
    //   qh [B,H,T,D]  @ 10 MB     (8 MB)
    //   kh            @ 18 MB     (8 MB)
    //   vt [B,H,D,T]  @ 26 MB     (8 MB)
    //   yf [B,T,C]    @ 34 MB     (8 MB)
    //   ervt [64,160] @ 44040192  (20480 B)
    //   erkb [129,64] @ 44060672  (16512 B)
    const size_t need = 44077184;
    if (ws_size < need) return;
    u16* xt   = (u16*)d_ws;
    u16* Wh   = (u16*)((char*)d_ws + 8388608);
    u16* qh   = (u16*)((char*)d_ws + 10485760);
    u16* kh   = (u16*)((char*)d_ws + 18874368);
    u16* vt   = (u16*)((char*)d_ws + 27262976);
    u16* yf   = (u16*)((char*)d_ws + 35651584);
    u16* ervt = (u16*)((char*)d_ws + 44040192);
    u16* erkb = (u16*)((char*)d_ws + 44060672);
    float* out = (float*)d_out;

    cast_all_kernel<<<dim3(2121), 256, 0, stream>>>(
        x, Wq, Wk, Wv, Wo, erk, erv, xt, Wh, ervt, erkb);
    proj_mfma<<<dim3(T_ / 128, H_, 3 * B_), 256, 0, stream>>>(
        xt, Wh, bq, bk, bv, qh, kh, vt);
    attn_kernel<<<dim3(2048), 256, 0, stream>>>(
        qh, kh, vt, erkb, ervt, xmask, yf);
    outproj_mfma<<<dim3(C_ / 64, B_ * (T_ / 64)), 256, 0, stream>>>(
        yf, Wh + ((size_t)3 << 18), bo, xmask, out);
}